// Round 16
// baseline (203.998 us; speedup 1.0000x reference)
//
#include <hip/hip_runtime.h>

typedef unsigned short u16;
typedef unsigned int u32;
typedef short vbf16x8 __attribute__((ext_vector_type(8)));   // 8 bf16 as shorts (4 VGPR)
typedef float vf32x4 __attribute__((ext_vector_type(4)));
typedef int vi32x4 __attribute__((ext_vector_type(4)));

#define MFMA16(a,b,c) __builtin_amdgcn_mfma_f32_16x16x32_bf16((a),(b),(c),0,0,0)

__device__ __forceinline__ u16 f2bf(float f) {
  union { float f; unsigned u; } c; c.f = f;
  unsigned r = c.u + 0x7fffu + ((c.u >> 16) & 1u);
  return (u16)(r >> 16);
}

// ---------------- prep: weight transposes (bf16) ----------------
__global__ __launch_bounds__(256) void k_prep_w(
    const float* __restrict__ w1, const float* __restrict__ w2,
    const float* __restrict__ u1, const float* __restrict__ u2,
    u16* __restrict__ wcatT, u16* __restrict__ w2T,
    u16* __restrict__ u1bT, u16* __restrict__ u2T) {
  int id = blockIdx.x * 256 + threadIdx.x;
  if (id < 49152) {
    int n = id >> 7, k = id & 127;
    float v;
    if (n < 128) v = w1[(128 + k) * 128 + n];
    else if (n < 256) v = w1[k * 128 + (n - 128)];
    else v = u1[k * 128 + (n - 256)];
    wcatT[id] = f2bf(v);
  } else {
    int id2 = id - 49152;
    int m = id2 >> 14, r = id2 & 16383;
    int n = r >> 7, k = r & 127;
    if (m == 0) w2T[r] = f2bf(w2[k * 128 + n]);
    else if (m == 1) u1bT[r] = f2bf(u1[(128 + k) * 128 + n]);
    else u2T[r] = f2bf(u2[k * 128 + n]);
  }
}

// ---------------- norms: xnf (f32), xbf (raw bf16), xnt (normalized bf16, MFMA-granule-tiled) ------
// xnt: granule (row j, ks, lg) at u16 offset (j>>4)*2048 + ks*512 + lg*128 + (j&15)*8.
__global__ __launch_bounds__(256) void k_norm(
    const float* __restrict__ x, float* __restrict__ xnf,
    u16* __restrict__ xnt, u16* __restrict__ xbf) {
  __shared__ u16 buf[4][128];
  int tid = threadIdx.x;
  int lane = tid & 63, w = tid >> 6;
  int row = blockIdx.x * 4 + w;
  size_t b = (size_t)row * 128;
  float v0 = x[b + lane], v1 = x[b + 64 + lane];
  float ss = v0 * v0 + v1 * v1;
  #pragma unroll
  for (int m = 32; m > 0; m >>= 1) ss += __shfl_xor(ss, m);
  float d = fmaxf(sqrtf(ss), 1e-8f);
  float n0 = v0 / d, n1 = v1 / d;
  xnf[b + lane] = n0; xnf[b + 64 + lane] = n1;
  xbf[b + lane] = f2bf(v0); xbf[b + 64 + lane] = f2bf(v1);
  buf[w][lane] = f2bf(n0); buf[w][64 + lane] = f2bf(n1);
  __syncthreads();
  if (tid < 64) {
    int r = tid >> 4, g = tid & 15;
    int grow = blockIdx.x * 4 + r;
    vi32x4 d4 = *(const vi32x4*)&buf[r][g * 8];
    *(vi32x4*)&xnt[(size_t)(grow >> 4) * 2048 + (g >> 2) * 512 + (g & 3) * 128 + (grow & 15) * 8] = d4;
  }
}

// ---------------- single sim pass: per-(row,seg-stream) top-3 FLOAT KEYS ---------------------------
// acc starts at 2.0 (C-operand of first MFMA does the +2 for free) -> acc[r] = sim+2 in (1,3].
// key = float_bits(acc) & ~0x3F | t  (t = 6-bit tile index; col = seg*1024 + t*16 + lr).
// Per-value cost: and_or + max + 2x med3 = 4 VALU.
// Block: 256 rows (4 waves x 64 rows) x one 1024-col segment. Grid 1024.
__global__ __launch_bounds__(256, 2) void k_sim1(
    const u16* __restrict__ xnt, u32* __restrict__ sampK) {
  const int tid = threadIdx.x, lane = tid & 63, w = tid >> 6;
  const int lr = lane & 15, lg = lane >> 4;
  const int seg = blockIdx.x & 15, rbk = blockIdx.x >> 4;
  const int rowbase = rbk * 256 + w * 64;

  vbf16x8 af[4][4];
  #pragma unroll
  for (int a = 0; a < 4; ++a) {
    const u16* tp = xnt + (size_t)((rowbase >> 4) + a) * 2048;
    #pragma unroll
    for (int ks = 0; ks < 4; ++ks)
      af[a][ks] = *(const vbf16x8*)(tp + ks * 512 + lg * 128 + lr * 8);
  }

  float k1[4][4], k2[4][4], k3[4][4];
  #pragma unroll
  for (int a = 0; a < 4; ++a)
    #pragma unroll
    for (int r = 0; r < 4; ++r) { k1[a][r] = 0.f; k2[a][r] = 0.f; k3[a][r] = 0.f; }

  const u16* segp = xnt + (size_t)(seg * 64) * 2048;
  vbf16x8 bc[4], bn[4];
  #pragma unroll
  for (int ks = 0; ks < 4; ++ks) bc[ks] = *(const vbf16x8*)(segp + ks * 512 + lane * 8);

  // acc seeded with 2.0; key build = single v_and_or; insert = max + 2x med3
#define S1STEP(B, TKEY) { \
  _Pragma("unroll") \
  for (int a = 0; a < 4; ++a) { \
    vf32x4 acc = {2.0f, 2.0f, 2.0f, 2.0f}; \
    _Pragma("unroll") \
    for (int ks = 0; ks < 4; ++ks) acc = MFMA16(af[a][ks], (B)[ks], acc); \
    _Pragma("unroll") \
    for (int r = 0; r < 4; ++r) { \
      union { u32 u; float f; } kc; \
      kc.u = (__float_as_uint(acc[r]) & 0xFFFFFFC0u) | (TKEY); \
      float kv = kc.f; \
      float nk1 = fmaxf(k1[a][r], kv); \
      float nk2 = __builtin_amdgcn_fmed3f(k1[a][r], k2[a][r], kv); \
      float nk3 = __builtin_amdgcn_fmed3f(k2[a][r], k3[a][r], kv); \
      k1[a][r] = nk1; k2[a][r] = nk2; k3[a][r] = nk3; \
    } } }

  #pragma unroll 1
  for (int ti = 0; ti < 32; ++ti) {
    { const u16* tp1 = segp + (size_t)(2 * ti + 1) * 2048;
      #pragma unroll
      for (int ks = 0; ks < 4; ++ks) bn[ks] = *(const vbf16x8*)(tp1 + ks * 512 + lane * 8); }
    S1STEP(bc, (u32)(2 * ti));
    { int nt = (ti < 31) ? (2 * ti + 2) : 63;
      const u16* tp2 = segp + (size_t)nt * 2048;
      #pragma unroll
      for (int ks = 0; ks < 4; ++ks) bc[ks] = *(const vbf16x8*)(tp2 + ks * 512 + lane * 8); }
    S1STEP(bn, (u32)(2 * ti + 1));
  }

  // dump 48 keys per (row, seg): sampK[row*768 + seg*48 + slot*16 + lr]
  #pragma unroll
  for (int a = 0; a < 4; ++a)
    #pragma unroll
    for (int r = 0; r < 4; ++r) {
      int row = rowbase + a * 16 + lg * 4 + r;
      u32* dp = sampK + (size_t)row * 768 + seg * 48;
      dp[lr] = __float_as_uint(k1[a][r]);
      dp[16 + lr] = __float_as_uint(k2[a][r]);
      dp[32 + lr] = __float_as_uint(k3[a][r]);
    }
}

// ---------------- merged cand+select: wave per row, ballot-bisection order statistics --------------
// theta: 24-iter u32 bisection (count >= 28 via per-lane 12-compare + 4 ballots) -> lo <= true 28th
// at every iteration (invariant), so capture guarantee is iteration-count-independent.
// mn: 24-iter float bisection (6 compares + 3 ballots) -> flo <= mn_true < flo + 1.8e-7.
// Replaces the 28x 6-deep-shfl extraction and the c-iteration pairwise rank loop of round 14.
__global__ __launch_bounds__(256) void k_candsel(
    const u32* __restrict__ sampK, const float* __restrict__ xnf,
    float* __restrict__ topV, int* __restrict__ topI) {
  __shared__ u32   keys3[4][256];    // only slot-2 (3rd-best) keys are ever read cross-lane
  __shared__ float svals[4][384];
  __shared__ int   sidx[4][384];
  __shared__ int   wlist[4][48];
  __shared__ float wex[4][48];
  const int tid = threadIdx.x, lane = tid & 63, w = tid >> 6;
  const int i = blockIdx.x * 4 + w;
  const u32* sp = sampK + (size_t)i * 768;
  u32 kq[12];
  #pragma unroll
  for (int q = 0; q < 12; ++q) {
    kq[q] = sp[q * 64 + lane];
    int f = q * 64 + lane;
    int i16 = f >> 4;
    int sg = (i16 * 171) >> 9;          // i16 / 3 (exact for 0..47)
    int slot = i16 - sg * 3;
    if (slot == 2) keys3[w][sg * 16 + (f & 15)] = kq[q];
  }

  // theta: bisect u32 key space for the 28th-largest; invariant count(>= lo) >= 28 -> lo <= true28
  u32 lo = 0x3F000000u, hi = 0x40600000u;   // keys = bits(sim+2) in (0.5, 3.5) always
  #pragma unroll 1
  for (int it = 0; it < 24; ++it) {
    u32 mid = lo + ((hi - lo) >> 1);
    int cl = 0;
    #pragma unroll
    for (int q = 0; q < 12; ++q) cl += (kq[q] >= mid) ? 1 : 0;
    int tot = __popcll(__ballot((cl & 1) != 0))
            + 2 * __popcll(__ballot((cl & 2) != 0))
            + 4 * __popcll(__ballot((cl & 4) != 0))
            + 8 * __popcll(__ballot((cl & 8) != 0));
    if (tot >= 28) lo = mid; else hi = mid;
  }
  // widen by 6e-3 in value space (> select window 5e-3 + quant slop)
  float dec = __uint_as_float(lo & 0xFFFFFFC0u);
  const u32 th = __float_as_uint(dec - 6e-3f) & 0xFFFFFFC0u;

  int cbase = 0;
  // keyed emission from UNFLAGGED streams -> LDS
  #pragma unroll
  for (int q = 0; q < 12; ++q) {
    int f = q * 64 + lane;
    int i16 = f >> 4;
    int sg = (i16 * 171) >> 9;
    int lrr = f & 15;
    u32 key3 = keys3[w][sg * 16 + lrr];
    bool e = (kq[q] >= th) && (key3 < th);
    unsigned long long ball = __ballot(e);
    if (e) {
      int pos = cbase + __popcll(ball & ((1ull << lane) - 1ull));
      if (pos < 384) {
        svals[w][pos] = __uint_as_float(kq[q] & 0xFFFFFFC0u) - 2.0f;
        sidx[w][pos] = sg * 1024 + (int)(kq[q] & 63u) * 16 + lrr;
      }
    }
    cbase += __popcll(ball);
  }
  if (cbase > 384) cbase = 384;
  // expansion: flagged streams -> all 64 member cols, sentinel value
  #pragma unroll 1
  for (int t = 0; t < 4; ++t) {
    int strm = t * 64 + lane;
    int sg = strm >> 4, lrr = strm & 15;
    bool fl = keys3[w][sg * 16 + lrr] >= th;
    unsigned long long mask = __ballot(fl);
    while (mask != 0ull && cbase + 64 <= 384) {
      int b = __ffsll((long long)mask) - 1;
      mask &= mask - 1ull;
      int strmb = t * 64 + b;
      int sgb = strmb >> 4, lrb = strmb & 15;
      svals[w][cbase + lane] = -1e30f;
      sidx[w][cbase + lane] = sgb * 1024 + lane * 16 + lrb;
      cbase += 64;
    }
  }
  const int c = cbase;

  const int g = lane >> 3, sl = lane & 7;
  const float* xip = &xnf[(size_t)i * 128 + sl * 16];
  vf32x4 xi0 = *(const vf32x4*)&xip[0];
  vf32x4 xi1 = *(const vf32x4*)&xip[4];
  vf32x4 xi2 = *(const vf32x4*)&xip[8];
  vf32x4 xi3 = *(const vf32x4*)&xip[12];

  // phase 0: exact rescore of sentinel (expansion) items
  #pragma unroll 1
  for (int s = g; s < c; s += 8) {
    if (svals[w][s] == -1e30f) {
      int j = sidx[w][s];
      const float* xjp = &xnf[(size_t)j * 128 + sl * 16];
      vf32x4 a0 = *(const vf32x4*)&xjp[0];
      vf32x4 a1 = *(const vf32x4*)&xjp[4];
      vf32x4 a2 = *(const vf32x4*)&xjp[8];
      vf32x4 a3 = *(const vf32x4*)&xjp[12];
      float p = xi0[0]*a0[0] + xi0[1]*a0[1] + xi0[2]*a0[2] + xi0[3]*a0[3]
              + xi1[0]*a1[0] + xi1[1]*a1[1] + xi1[2]*a1[2] + xi1[3]*a1[3]
              + xi2[0]*a2[0] + xi2[1]*a2[1] + xi2[2]*a2[2] + xi2[3]*a2[3]
              + xi3[0]*a3[0] + xi3[1]*a3[1] + xi3[2]*a3[2] + xi3[3]*a3[3];
      p += __shfl_xor(p, 1); p += __shfl_xor(p, 2); p += __shfl_xor(p, 4);
      if (sl == 0) svals[w][s] = p;
    }
  }

  // load per-lane candidate slices
  float v[6]; int ix[6]; bool ok[6];
  #pragma unroll
  for (int h = 0; h < 6; ++h) {
    int s = h * 64 + lane;
    ok[h] = s < c;
    v[h] = ok[h] ? svals[w][s] : -1e30f;
    ix[h] = ok[h] ? sidx[w][s] : 0x7fffffff;
  }

  // mn: bisect float space for the 20th-largest captured v; flo <= mn_true < flo + 1.8e-7
  float flo = -1.5f, fhi = 1.5f;
  #pragma unroll 1
  for (int it = 0; it < 24; ++it) {
    float mid = 0.5f * (flo + fhi);
    int cl = 0;
    #pragma unroll
    for (int h = 0; h < 6; ++h) cl += (ok[h] && v[h] >= mid) ? 1 : 0;
    int tot = __popcll(__ballot((cl & 1) != 0))
            + 2 * __popcll(__ballot((cl & 2) != 0))
            + 4 * __popcll(__ballot((cl & 4) != 0));
    if (tot >= 20) flo = mid; else fhi = mid;
  }

  // A / W classification (bisection slack 1.8e-7 absorbed by +1e-5 guard)
  const float M2 = 5e-3f;
  const float aThr = flo + M2 + 1e-5f;
  const float wLo  = flo - M2;
  bool isA[6], isW[6]; int wp[6];
  int nA = 0, wbase = 0;
  #pragma unroll
  for (int h = 0; h < 6; ++h) {
    isA[h] = ok[h] && v[h] > aThr;
    isW[h] = ok[h] && (v[h] >= wLo) && (v[h] <= aThr);
    unsigned long long ba = __ballot(isA[h]);
    nA += __popcll(ba);
    unsigned long long bw = __ballot(isW[h]);
    wp[h] = wbase + __popcll(bw & ((1ull << lane) - 1ull));
    if (isW[h] && wp[h] < 48) wlist[w][wp[h]] = ix[h];
    wbase += __popcll(bw);
  }
  int nW = (wbase > 48) ? 48 : wbase;

  // exact rescore of W (8 groups x 8 lanes)
  #pragma unroll 1
  for (int t = g; t < nW; t += 8) {
    int j = wlist[w][t];
    const float* xjp = &xnf[(size_t)j * 128 + sl * 16];
    vf32x4 a0 = *(const vf32x4*)&xjp[0];
    vf32x4 a1 = *(const vf32x4*)&xjp[4];
    vf32x4 a2 = *(const vf32x4*)&xjp[8];
    vf32x4 a3 = *(const vf32x4*)&xjp[12];
    float p = xi0[0]*a0[0] + xi0[1]*a0[1] + xi0[2]*a0[2] + xi0[3]*a0[3]
            + xi1[0]*a1[0] + xi1[1]*a1[1] + xi1[2]*a1[2] + xi1[3]*a1[3]
            + xi2[0]*a2[0] + xi2[1]*a2[1] + xi2[2]*a2[2] + xi2[3]*a2[3]
            + xi3[0]*a3[0] + xi3[1]*a3[1] + xi3[2]*a3[2] + xi3[3]*a3[3];
    p += __shfl_xor(p, 1); p += __shfl_xor(p, 2); p += __shfl_xor(p, 4);
    if (sl == 0) wex[w][t] = p;
  }

  float e[6]; int rw[6];
  #pragma unroll
  for (int h = 0; h < 6; ++h) { e[h] = -1e30f; rw[h] = 0; }
  #pragma unroll
  for (int h = 0; h < 6; ++h)
    if (isW[h] && wp[h] < 48) e[h] = wex[w][wp[h]];
  #pragma unroll 1
  for (int t = 0; t < nW; ++t) {
    float et = wex[w][t]; int jt = wlist[w][t];
    #pragma unroll
    for (int h = 0; h < 6; ++h)
      rw[h] += (et > e[h] || (et == e[h] && jt < ix[h])) ? 1 : 0;
  }
  const int need = 20 - nA;
  int base = 0;
  #pragma unroll
  for (int h = 0; h < 6; ++h) {
    bool fw = isW[h] && (wp[h] < 48) && rw[h] < need;
    bool fin = isA[h] || fw;
    float o = isA[h] ? v[h] : e[h];
    unsigned long long bf = __ballot(fin);
    if (fin) {
      int pos = base + __popcll(bf & ((1ull << lane) - 1ull));
      topV[(size_t)i * 20 + pos] = o; topI[(size_t)i * 20 + pos] = ix[h];
    }
    base += __popcll(bf);
  }
}

// ---------------- precompute U = x@w1[128:], T = x@w1[:128], V = x@uw1[:128] ----------------
__global__ __launch_bounds__(256) void k_pre(
    const u16* __restrict__ xbf, const u16* __restrict__ wcatT,
    float* __restrict__ U, float* __restrict__ T, float* __restrict__ V) {
  const int tid = threadIdx.x, lane = tid & 63, w = tid >> 6;
  const int lr = lane & 15, lg = lane >> 4;
  const int rowbase = blockIdx.x * 64, cb = blockIdx.y;
  const int a = w >> 1, b = w & 1;
  vbf16x8 af[2][4];
  #pragma unroll
  for (int ar = 0; ar < 2; ++ar) {
    const u16* rp = xbf + (size_t)(rowbase + (a * 2 + ar) * 16 + lr) * 128;
    #pragma unroll
    for (int ks = 0; ks < 4; ++ks) af[ar][ks] = *(const vbf16x8*)(rp + ks * 32 + lg * 8);
  }
  vf32x4 z = {0.f, 0.f, 0.f, 0.f};
  vf32x4 acc[2][2] = {{z, z}, {z, z}};
  #pragma unroll
  for (int ks = 0; ks < 4; ++ks) {
    vbf16x8 bf[2];
    #pragma unroll
    for (int cbl = 0; cbl < 2; ++cbl) {
      int gcol = cb * 64 + (b * 2 + cbl) * 16 + lr;
      bf[cbl] = *(const vbf16x8*)(wcatT + (size_t)gcol * 128 + ks * 32 + lg * 8);
    }
    #pragma unroll
    for (int ar = 0; ar < 2; ++ar)
      #pragma unroll
      for (int cbl = 0; cbl < 2; ++cbl)
        acc[ar][cbl] = MFMA16(af[ar][ks], bf[cbl], acc[ar][cbl]);
  }
  #pragma unroll
  for (int ar = 0; ar < 2; ++ar)
    #pragma unroll
    for (int cbl = 0; cbl < 2; ++cbl) {
      int gcol = cb * 64 + (b * 2 + cbl) * 16 + lr;
      #pragma unroll
      for (int r = 0; r < 4; ++r) {
        int grow = rowbase + (a * 2 + ar) * 16 + lg * 4 + r;
        float vv = acc[ar][cbl][r];
        if (gcol < 128)      U[(size_t)grow * 128 + gcol] = vv;
        else if (gcol < 256) T[(size_t)grow * 128 + (gcol - 128)] = vv;
        else                 V[(size_t)grow * 128 + (gcol - 256)] = vv;
      }
    }
}

// ---------------- fused: softmax, G = sum_e s_e*relu(T_i+U_j+b1), h_agg, update MLP ----------------
__global__ __launch_bounds__(256) void k_msg_upd(
    const float* __restrict__ x,
    const float* __restrict__ Uarr, const float* __restrict__ Tarr, const float* __restrict__ Varr,
    const float* __restrict__ topV, const int* __restrict__ topI,
    const float* __restrict__ b1, const float* __restrict__ b2,
    const float* __restrict__ ub1, const float* __restrict__ ub2,
    const u16* __restrict__ w2T, const u16* __restrict__ u1bT, const u16* __restrict__ u2T,
    float* __restrict__ out) {
  __shared__ float wsm[32 * 20];
  __shared__ int   ism[32 * 20];
  __shared__ u16   Gbf[32 * 136];
  __shared__ u16   Hbf[32 * 136];
  const int tid = threadIdx.x, lane = tid & 63, w = tid >> 6;
  const int lr = lane & 15, lg = lane >> 4;
  const int base = blockIdx.x * 32;

  if (tid < 32) { // softmax over top-20 sims (order-independent)
    int i = base + tid;
    float vv[20]; float mx = -1e30f;
    #pragma unroll
    for (int e = 0; e < 20; ++e) { vv[e] = topV[(size_t)i * 20 + e]; mx = fmaxf(mx, vv[e]); }
    float s = 0.f;
    #pragma unroll
    for (int e = 0; e < 20; ++e) { vv[e] = __expf(vv[e] - mx); s += vv[e]; }
    float inv = 1.f / s;
    #pragma unroll
    for (int e = 0; e < 20; ++e) {
      wsm[tid * 20 + e] = vv[e] * inv;
      ism[tid * 20 + e] = topI[(size_t)i * 20 + e];
    }
  }
  __syncthreads();

  { // G step: 8 threads per row, 16 channels each
    int r = tid >> 3, q = tid & 7, ch0 = q * 16;
    int i = base + r;
    vf32x4 z = {0.f, 0.f, 0.f, 0.f};
    vf32x4 tr[4], br[4], acc[4];
    #pragma unroll
    for (int c = 0; c < 4; ++c) {
      tr[c] = *(const vf32x4*)&Tarr[(size_t)i * 128 + ch0 + c * 4];
      br[c] = *(const vf32x4*)&b1[ch0 + c * 4];
      acc[c] = z;
    }
    #pragma unroll 1
    for (int e = 0; e < 20; ++e) {
      int j = ism[r * 20 + e]; float s = wsm[r * 20 + e];
      const vf32x4* up = (const vf32x4*)&Uarr[(size_t)j * 128 + ch0];
      #pragma unroll
      for (int c = 0; c < 4; ++c) {
        vf32x4 u = up[c];
        #pragma unroll
        for (int zz = 0; zz < 4; ++zz) {
          float p = tr[c][zz] + u[zz] + br[c][zz];
          acc[c][zz] += s * fmaxf(p, 0.f);
        }
      }
    }
    #pragma unroll
    for (int c = 0; c < 4; ++c)
      #pragma unroll
      for (int zz = 0; zz < 4; ++zz)
        Gbf[r * 136 + ch0 + c * 4 + zz] = f2bf(acc[c][zz]);
  }
  __syncthreads();

  const int rt = w >> 1, cg = w & 1;
  vf32x4 z4 = {0.f, 0.f, 0.f, 0.f};
  { // GEMM1: h_agg = G @ w2 + b2 -> Hbf
    vf32x4 acc[4] = {z4, z4, z4, z4};
    #pragma unroll
    for (int ks = 0; ks < 4; ++ks) {
      vbf16x8 a = *(const vbf16x8*)&Gbf[(rt * 16 + lr) * 136 + ks * 32 + lg * 8];
      #pragma unroll
      for (int c = 0; c < 4; ++c) {
        int col = (cg * 4 + c) * 16 + lr;
        vbf16x8 bb = *(const vbf16x8*)(w2T + (size_t)col * 128 + ks * 32 + lg * 8);
        acc[c] = MFMA16(a, bb, acc[c]);
      }
    }
    #pragma unroll
    for (int c = 0; c < 4; ++c) {
      int col = (cg * 4 + c) * 16 + lr;
      float bias = b2[col];
      #pragma unroll
      for (int r = 0; r < 4; ++r) {
        int row = rt * 16 + lg * 4 + r;
        Hbf[row * 136 + col] = f2bf(acc[c][r] + bias);
      }
    }
  }
  __syncthreads();
  { // GEMM2: pre = h_agg @ uw1[128:] + V_i + ub1, relu -> Gbf (reused as P)
    vf32x4 acc[4] = {z4, z4, z4, z4};
    #pragma unroll
    for (int ks = 0; ks < 4; ++ks) {
      vbf16x8 a = *(const vbf16x8*)&Hbf[(rt * 16 + lr) * 136 + ks * 32 + lg * 8];
      #pragma unroll
      for (int c = 0; c < 4; ++c) {
        int col = (cg * 4 + c) * 16 + lr;
        vbf16x8 bb = *(const vbf16x8*)(u1bT + (size_t)col * 128 + ks * 32 + lg * 8);
        acc[c] = MFMA16(a, bb, acc[c]);
      }
    }
    #pragma unroll
    for (int c = 0; c < 4; ++c) {
      int col = (cg * 4 + c) * 16 + lr;
      float bias = ub1[col];
      #pragma unroll
      for (int r = 0; r < 4; ++r) {
        int row = rt * 16 + lg * 4 + r;
        float vv = acc[c][r] + Varr[(size_t)(base + row) * 128 + col] + bias;
        Gbf[row * 136 + col] = f2bf(fmaxf(vv, 0.f));
      }
    }
  }
  __syncthreads();
  { // GEMM3: out = x + P @ uw2 + ub2
    vf32x4 acc[4] = {z4, z4, z4, z4};
    #pragma unroll
    for (int ks = 0; ks < 4; ++ks) {
      vbf16x8 a = *(const vbf16x8*)&Gbf[(rt * 16 + lr) * 136 + ks * 32 + lg * 8];
      #pragma unroll
      for (int c = 0; c < 4; ++c) {
        int col = (cg * 4 + c) * 16 + lr;
        vbf16x8 bb = *(const vbf16x8*)(u2T + (size_t)col * 128 + ks * 32 + lg * 8);
        acc[c] = MFMA16(a, bb, acc[c]);
      }
    }
    #pragma unroll
    for (int c = 0; c < 4; ++c) {
      int col = (cg * 4 + c) * 16 + lr;
      float bias = ub2[col];
      #pragma unroll
      for (int r = 0; r < 4; ++r) {
        int row = rt * 16 + lg * 4 + r;
        size_t o = (size_t)(base + row) * 128 + col;
        out[o] = x[o] + acc[c][r] + bias;
      }
    }
  }
}

extern "C" void kernel_launch(void* const* d_in, const int* in_sizes, int n_in,
                              void* d_out, int out_size, void* d_ws, size_t ws_size,
                              hipStream_t stream) {
  (void)in_sizes; (void)n_in; (void)out_size; (void)ws_size;
  const float* x   = (const float*)d_in[0];
  const float* w1  = (const float*)d_in[1];
  const float* b1  = (const float*)d_in[2];
  const float* w2  = (const float*)d_in[3];
  const float* b2  = (const float*)d_in[4];
  const float* uw1 = (const float*)d_in[5];
  const float* ub1 = (const float*)d_in[6];
  const float* uw2 = (const float*)d_in[7];
  const float* ub2 = (const float*)d_in[8];
  float* out = (float*)d_out;
  char* ws = (char*)d_ws;

  // Live ranges: sampK [17M,65M) written by k_sim1, read by k_candsel.
  // U/T/V @ [17M,41M) written by k_pre AFTER k_candsel -> overlay OK. High-water ~67.6 MB.
  u16*   xnt   = (u16*)(ws + 0);                         // 4 MB (granule-tiled xn)
  u16*   xbf   = (u16*)(ws + (4u << 20));                // 4 MB
  float* xnf   = (float*)(ws + (8u << 20));              // 8 MB
  u16*   wcatT = (u16*)(ws + (16u << 20));               // 96 KB
  u16*   w2T   = (u16*)(ws + (16u << 20) + 131072);      // 32 KB
  u16*   u1bT  = (u16*)(ws + (16u << 20) + 163840);      // 32 KB
  u16*   u2T   = (u16*)(ws + (16u << 20) + 196608);      // 32 KB
  u32*   sampK = (u32*)(ws + (17u << 20));               // 48 MB (transient)
  float* Uarr  = (float*)(ws + (17u << 20));             // 8 MB (after sampK dead)
  float* Tarr  = (float*)(ws + (25u << 20));             // 8 MB
  float* Varr  = (float*)(ws + (33u << 20));             // 8 MB
  float* topV  = (float*)(ws + (65u << 20));             // 1.31 MB
  int*   topI  = (int*)(ws + (67u << 20));               // 1.31 MB

  hipLaunchKernelGGL(k_prep_w, dim3(384), dim3(256), 0, stream,
                     w1, w2, uw1, uw2, wcatT, w2T, u1bT, u2T);
  hipLaunchKernelGGL(k_norm, dim3(4096), dim3(256), 0, stream, x, xnf, xnt, xbf);
  hipLaunchKernelGGL(k_sim1, dim3(1024), dim3(256), 0, stream, xnt, sampK);
  hipLaunchKernelGGL(k_candsel, dim3(4096), dim3(256), 0, stream, sampK, xnf, topV, topI);
  hipLaunchKernelGGL(k_pre, dim3(256, 6), dim3(256), 0, stream, xbf, wcatT, Uarr, Tarr, Varr);
  hipLaunchKernelGGL(k_msg_upd, dim3(512), dim3(256), 0, stream,
                     x, Uarr, Tarr, Varr, topV, topI, b1, b2, ub1, ub2, w2T, u1bT, u2T, out);
}

// Round 17
// 192.573 us; speedup vs baseline: 1.0593x; 1.0593x over previous
//
#include <hip/hip_runtime.h>

typedef unsigned short u16;
typedef unsigned int u32;
typedef short vbf16x8 __attribute__((ext_vector_type(8)));   // 8 bf16 as shorts (4 VGPR)
typedef float vf32x4 __attribute__((ext_vector_type(4)));
typedef int vi32x4 __attribute__((ext_vector_type(4)));

#define MFMA16(a,b,c) __builtin_amdgcn_mfma_f32_16x16x32_bf16((a),(b),(c),0,0,0)

__device__ __forceinline__ u16 f2bf(float f) {
  union { float f; unsigned u; } c; c.f = f;
  unsigned r = c.u + 0x7fffu + ((c.u >> 16) & 1u);
  return (u16)(r >> 16);
}

// ---------------- prep: weight transposes (bf16) ----------------
__global__ __launch_bounds__(256) void k_prep_w(
    const float* __restrict__ w1, const float* __restrict__ w2,
    const float* __restrict__ u1, const float* __restrict__ u2,
    u16* __restrict__ wcatT, u16* __restrict__ w2T,
    u16* __restrict__ u1bT, u16* __restrict__ u2T) {
  int id = blockIdx.x * 256 + threadIdx.x;
  if (id < 49152) {
    int n = id >> 7, k = id & 127;
    float v;
    if (n < 128) v = w1[(128 + k) * 128 + n];
    else if (n < 256) v = w1[k * 128 + (n - 128)];
    else v = u1[k * 128 + (n - 256)];
    wcatT[id] = f2bf(v);
  } else {
    int id2 = id - 49152;
    int m = id2 >> 14, r = id2 & 16383;
    int n = r >> 7, k = r & 127;
    if (m == 0) w2T[r] = f2bf(w2[k * 128 + n]);
    else if (m == 1) u1bT[r] = f2bf(u1[(128 + k) * 128 + n]);
    else u2T[r] = f2bf(u2[k * 128 + n]);
  }
}

// ---------------- norms: xnf (f32), xbf (raw bf16), xnt (normalized bf16, MFMA-granule-tiled) ------
// xnt: granule (row j, ks, lg) at u16 offset (j>>4)*2048 + ks*512 + lg*128 + (j&15)*8.
__global__ __launch_bounds__(256) void k_norm(
    const float* __restrict__ x, float* __restrict__ xnf,
    u16* __restrict__ xnt, u16* __restrict__ xbf) {
  __shared__ u16 buf[4][128];
  int tid = threadIdx.x;
  int lane = tid & 63, w = tid >> 6;
  int row = blockIdx.x * 4 + w;
  size_t b = (size_t)row * 128;
  float v0 = x[b + lane], v1 = x[b + 64 + lane];
  float ss = v0 * v0 + v1 * v1;
  #pragma unroll
  for (int m = 32; m > 0; m >>= 1) ss += __shfl_xor(ss, m);
  float d = fmaxf(sqrtf(ss), 1e-8f);
  float n0 = v0 / d, n1 = v1 / d;
  xnf[b + lane] = n0; xnf[b + 64 + lane] = n1;
  xbf[b + lane] = f2bf(v0); xbf[b + 64 + lane] = f2bf(v1);
  buf[w][lane] = f2bf(n0); buf[w][64 + lane] = f2bf(n1);
  __syncthreads();
  if (tid < 64) {
    int r = tid >> 4, g = tid & 15;
    int grow = blockIdx.x * 4 + r;
    vi32x4 d4 = *(const vi32x4*)&buf[r][g * 8];
    *(vi32x4*)&xnt[(size_t)(grow >> 4) * 2048 + (g >> 2) * 512 + (g & 3) * 128 + (grow & 15) * 8] = d4;
  }
}

// ---------------- single sim pass: per-(row,seg-stream) top-3 FLOAT KEYS ---------------------------
// two4 = {2,2,2,2} persistent register fed as C of the FIRST MFMA (D gets fresh regs -> no acc-init
// movs; was ~16 issue slots/step). acc[r] = sim+2 in (1,3].
// key = float_bits(acc) & ~0x3F | t; per-value cost: and_or + max + 2x med3 = 4 VALU.
// Block: 256 rows (4 waves x 64 rows) x one 1024-col segment. Grid 1024.
__global__ __launch_bounds__(256, 2) void k_sim1(
    const u16* __restrict__ xnt, u32* __restrict__ sampK) {
  const int tid = threadIdx.x, lane = tid & 63, w = tid >> 6;
  const int lr = lane & 15, lg = lane >> 4;
  const int seg = blockIdx.x & 15, rbk = blockIdx.x >> 4;
  const int rowbase = rbk * 256 + w * 64;

  vbf16x8 af[4][4];
  #pragma unroll
  for (int a = 0; a < 4; ++a) {
    const u16* tp = xnt + (size_t)((rowbase >> 4) + a) * 2048;
    #pragma unroll
    for (int ks = 0; ks < 4; ++ks)
      af[a][ks] = *(const vbf16x8*)(tp + ks * 512 + lg * 128 + lr * 8);
  }

  float k1[4][4], k2[4][4], k3[4][4];
  #pragma unroll
  for (int a = 0; a < 4; ++a)
    #pragma unroll
    for (int r = 0; r < 4; ++r) { k1[a][r] = 0.f; k2[a][r] = 0.f; k3[a][r] = 0.f; }

  const vf32x4 two4 = {2.0f, 2.0f, 2.0f, 2.0f};

  const u16* segp = xnt + (size_t)(seg * 64) * 2048;
  vbf16x8 bc[4], bn[4];
  #pragma unroll
  for (int ks = 0; ks < 4; ++ks) bc[ks] = *(const vbf16x8*)(segp + ks * 512 + lane * 8);

#define S1STEP(B, TKEY) { \
  _Pragma("unroll") \
  for (int a = 0; a < 4; ++a) { \
    vf32x4 acc = MFMA16(af[a][0], (B)[0], two4); \
    _Pragma("unroll") \
    for (int ks = 1; ks < 4; ++ks) acc = MFMA16(af[a][ks], (B)[ks], acc); \
    _Pragma("unroll") \
    for (int r = 0; r < 4; ++r) { \
      union { u32 u; float f; } kc; \
      kc.u = (__float_as_uint(acc[r]) & 0xFFFFFFC0u) | (TKEY); \
      float kv = kc.f; \
      float nk1 = fmaxf(k1[a][r], kv); \
      float nk2 = __builtin_amdgcn_fmed3f(k1[a][r], k2[a][r], kv); \
      float nk3 = __builtin_amdgcn_fmed3f(k2[a][r], k3[a][r], kv); \
      k1[a][r] = nk1; k2[a][r] = nk2; k3[a][r] = nk3; \
    } } }

  #pragma unroll 1
  for (int ti = 0; ti < 32; ++ti) {
    { const u16* tp1 = segp + (size_t)(2 * ti + 1) * 2048;
      #pragma unroll
      for (int ks = 0; ks < 4; ++ks) bn[ks] = *(const vbf16x8*)(tp1 + ks * 512 + lane * 8); }
    S1STEP(bc, (u32)(2 * ti));
    { int nt = (ti < 31) ? (2 * ti + 2) : 63;
      const u16* tp2 = segp + (size_t)nt * 2048;
      #pragma unroll
      for (int ks = 0; ks < 4; ++ks) bc[ks] = *(const vbf16x8*)(tp2 + ks * 512 + lane * 8); }
    S1STEP(bn, (u32)(2 * ti + 1));
  }

  // dump 48 keys per (row, seg): sampK[row*768 + seg*48 + slot*16 + lr]
  #pragma unroll
  for (int a = 0; a < 4; ++a)
    #pragma unroll
    for (int r = 0; r < 4; ++r) {
      int row = rowbase + a * 16 + lg * 4 + r;
      u32* dp = sampK + (size_t)row * 768 + seg * 48;
      dp[lr] = __float_as_uint(k1[a][r]);
      dp[16 + lr] = __float_as_uint(k2[a][r]);
      dp[32 + lr] = __float_as_uint(k3[a][r]);
    }
}

// ---------------- merged cand+select: wave per row, ballot-bisection order statistics --------------
// theta: 14-iter u32 bisection; invariant lo <= true-28th at EVERY iteration, so shortening only
// widens capture by <= 3.4e-4 (safe direction). mn: 16-iter float bisection, slack 4.6e-5
// absorbed by the +6e-5 A-guard. Margin chain: capture >= 28th-6e-3 covers window wLo = flo-5e-3
// since 28th <= 20th <= flo+4.6e-5 (1e-3 headroom).
__global__ __launch_bounds__(256) void k_candsel(
    const u32* __restrict__ sampK, const float* __restrict__ xnf,
    float* __restrict__ topV, int* __restrict__ topI) {
  __shared__ u32   keys3[4][256];    // only slot-2 (3rd-best) keys are ever read cross-lane
  __shared__ float svals[4][384];
  __shared__ int   sidx[4][384];
  __shared__ int   wlist[4][48];
  __shared__ float wex[4][48];
  const int tid = threadIdx.x, lane = tid & 63, w = tid >> 6;
  const int i = blockIdx.x * 4 + w;
  const u32* sp = sampK + (size_t)i * 768;
  u32 kq[12];
  #pragma unroll
  for (int q = 0; q < 12; ++q) {
    kq[q] = sp[q * 64 + lane];
    int f = q * 64 + lane;
    int i16 = f >> 4;
    int sg = (i16 * 171) >> 9;          // i16 / 3 (exact for 0..47)
    int slot = i16 - sg * 3;
    if (slot == 2) keys3[w][sg * 16 + (f & 15)] = kq[q];
  }

  // theta: bisect u32 key space for the 28th-largest; lo <= true28 invariant
  u32 lo = 0x3F000000u, hi = 0x40600000u;   // keys = bits(sim+2) in (0.5, 3.5) always
  #pragma unroll 1
  for (int it = 0; it < 14; ++it) {
    u32 mid = lo + ((hi - lo) >> 1);
    int cl = 0;
    #pragma unroll
    for (int q = 0; q < 12; ++q) cl += (kq[q] >= mid) ? 1 : 0;
    int tot = __popcll(__ballot((cl & 1) != 0))
            + 2 * __popcll(__ballot((cl & 2) != 0))
            + 4 * __popcll(__ballot((cl & 4) != 0))
            + 8 * __popcll(__ballot((cl & 8) != 0));
    if (tot >= 28) lo = mid; else hi = mid;
  }
  // widen by 6e-3 in value space (> select window 5e-3 + bisection/quant slop)
  float dec = __uint_as_float(lo & 0xFFFFFFC0u);
  const u32 th = __float_as_uint(dec - 6e-3f) & 0xFFFFFFC0u;

  int cbase = 0;
  // keyed emission from UNFLAGGED streams -> LDS
  #pragma unroll
  for (int q = 0; q < 12; ++q) {
    int f = q * 64 + lane;
    int i16 = f >> 4;
    int sg = (i16 * 171) >> 9;
    int lrr = f & 15;
    u32 key3 = keys3[w][sg * 16 + lrr];
    bool e = (kq[q] >= th) && (key3 < th);
    unsigned long long ball = __ballot(e);
    if (e) {
      int pos = cbase + __popcll(ball & ((1ull << lane) - 1ull));
      if (pos < 384) {
        svals[w][pos] = __uint_as_float(kq[q] & 0xFFFFFFC0u) - 2.0f;
        sidx[w][pos] = sg * 1024 + (int)(kq[q] & 63u) * 16 + lrr;
      }
    }
    cbase += __popcll(ball);
  }
  if (cbase > 384) cbase = 384;
  // expansion: flagged streams -> all 64 member cols, sentinel value
  #pragma unroll 1
  for (int t = 0; t < 4; ++t) {
    int strm = t * 64 + lane;
    int sg = strm >> 4, lrr = strm & 15;
    bool fl = keys3[w][sg * 16 + lrr] >= th;
    unsigned long long mask = __ballot(fl);
    while (mask != 0ull && cbase + 64 <= 384) {
      int b = __ffsll((long long)mask) - 1;
      mask &= mask - 1ull;
      int strmb = t * 64 + b;
      int sgb = strmb >> 4, lrb = strmb & 15;
      svals[w][cbase + lane] = -1e30f;
      sidx[w][cbase + lane] = sgb * 1024 + lane * 16 + lrb;
      cbase += 64;
    }
  }
  const int c = cbase;

  const int g = lane >> 3, sl = lane & 7;
  const float* xip = &xnf[(size_t)i * 128 + sl * 16];
  vf32x4 xi0 = *(const vf32x4*)&xip[0];
  vf32x4 xi1 = *(const vf32x4*)&xip[4];
  vf32x4 xi2 = *(const vf32x4*)&xip[8];
  vf32x4 xi3 = *(const vf32x4*)&xip[12];

  // phase 0: exact rescore of sentinel (expansion) items
  #pragma unroll 1
  for (int s = g; s < c; s += 8) {
    if (svals[w][s] == -1e30f) {
      int j = sidx[w][s];
      const float* xjp = &xnf[(size_t)j * 128 + sl * 16];
      vf32x4 a0 = *(const vf32x4*)&xjp[0];
      vf32x4 a1 = *(const vf32x4*)&xjp[4];
      vf32x4 a2 = *(const vf32x4*)&xjp[8];
      vf32x4 a3 = *(const vf32x4*)&xjp[12];
      float p = xi0[0]*a0[0] + xi0[1]*a0[1] + xi0[2]*a0[2] + xi0[3]*a0[3]
              + xi1[0]*a1[0] + xi1[1]*a1[1] + xi1[2]*a1[2] + xi1[3]*a1[3]
              + xi2[0]*a2[0] + xi2[1]*a2[1] + xi2[2]*a2[2] + xi2[3]*a2[3]
              + xi3[0]*a3[0] + xi3[1]*a3[1] + xi3[2]*a3[2] + xi3[3]*a3[3];
      p += __shfl_xor(p, 1); p += __shfl_xor(p, 2); p += __shfl_xor(p, 4);
      if (sl == 0) svals[w][s] = p;
    }
  }

  // load per-lane candidate slices
  float v[6]; int ix[6]; bool ok[6];
  #pragma unroll
  for (int h = 0; h < 6; ++h) {
    int s = h * 64 + lane;
    ok[h] = s < c;
    v[h] = ok[h] ? svals[w][s] : -1e30f;
    ix[h] = ok[h] ? sidx[w][s] : 0x7fffffff;
  }

  // mn: bisect float space for the 20th-largest captured v; flo <= mn_true < flo + 4.6e-5
  float flo = -1.5f, fhi = 1.5f;
  #pragma unroll 1
  for (int it = 0; it < 16; ++it) {
    float mid = 0.5f * (flo + fhi);
    int cl = 0;
    #pragma unroll
    for (int h = 0; h < 6; ++h) cl += (ok[h] && v[h] >= mid) ? 1 : 0;
    int tot = __popcll(__ballot((cl & 1) != 0))
            + 2 * __popcll(__ballot((cl & 2) != 0))
            + 4 * __popcll(__ballot((cl & 4) != 0));
    if (tot >= 20) flo = mid; else fhi = mid;
  }

  // A / W classification (bisection slack 4.6e-5 absorbed by +6e-5 guard)
  const float M2 = 5e-3f;
  const float aThr = flo + M2 + 6e-5f;
  const float wLo  = flo - M2;
  bool isA[6], isW[6]; int wp[6];
  int nA = 0, wbase = 0;
  #pragma unroll
  for (int h = 0; h < 6; ++h) {
    isA[h] = ok[h] && v[h] > aThr;
    isW[h] = ok[h] && (v[h] >= wLo) && (v[h] <= aThr);
    unsigned long long ba = __ballot(isA[h]);
    nA += __popcll(ba);
    unsigned long long bw = __ballot(isW[h]);
    wp[h] = wbase + __popcll(bw & ((1ull << lane) - 1ull));
    if (isW[h] && wp[h] < 48) wlist[w][wp[h]] = ix[h];
    wbase += __popcll(bw);
  }
  int nW = (wbase > 48) ? 48 : wbase;

  // exact rescore of W (8 groups x 8 lanes)
  #pragma unroll 1
  for (int t = g; t < nW; t += 8) {
    int j = wlist[w][t];
    const float* xjp = &xnf[(size_t)j * 128 + sl * 16];
    vf32x4 a0 = *(const vf32x4*)&xjp[0];
    vf32x4 a1 = *(const vf32x4*)&xjp[4];
    vf32x4 a2 = *(const vf32x4*)&xjp[8];
    vf32x4 a3 = *(const vf32x4*)&xjp[12];
    float p = xi0[0]*a0[0] + xi0[1]*a0[1] + xi0[2]*a0[2] + xi0[3]*a0[3]
            + xi1[0]*a1[0] + xi1[1]*a1[1] + xi1[2]*a1[2] + xi1[3]*a1[3]
            + xi2[0]*a2[0] + xi2[1]*a2[1] + xi2[2]*a2[2] + xi2[3]*a2[3]
            + xi3[0]*a3[0] + xi3[1]*a3[1] + xi3[2]*a3[2] + xi3[3]*a3[3];
    p += __shfl_xor(p, 1); p += __shfl_xor(p, 2); p += __shfl_xor(p, 4);
    if (sl == 0) wex[w][t] = p;
  }

  float e[6]; int rw[6];
  #pragma unroll
  for (int h = 0; h < 6; ++h) { e[h] = -1e30f; rw[h] = 0; }
  #pragma unroll
  for (int h = 0; h < 6; ++h)
    if (isW[h] && wp[h] < 48) e[h] = wex[w][wp[h]];
  #pragma unroll 1
  for (int t = 0; t < nW; ++t) {
    float et = wex[w][t]; int jt = wlist[w][t];
    #pragma unroll
    for (int h = 0; h < 6; ++h)
      rw[h] += (et > e[h] || (et == e[h] && jt < ix[h])) ? 1 : 0;
  }
  const int need = 20 - nA;
  int base = 0;
  #pragma unroll
  for (int h = 0; h < 6; ++h) {
    bool fw = isW[h] && (wp[h] < 48) && rw[h] < need;
    bool fin = isA[h] || fw;
    float o = isA[h] ? v[h] : e[h];
    unsigned long long bf = __ballot(fin);
    if (fin) {
      int pos = base + __popcll(bf & ((1ull << lane) - 1ull));
      topV[(size_t)i * 20 + pos] = o; topI[(size_t)i * 20 + pos] = ix[h];
    }
    base += __popcll(bf);
  }
}

// ---------------- precompute U = x@w1[128:], T = x@w1[:128], V = x@uw1[:128] ----------------
__global__ __launch_bounds__(256) void k_pre(
    const u16* __restrict__ xbf, const u16* __restrict__ wcatT,
    float* __restrict__ U, float* __restrict__ T, float* __restrict__ V) {
  const int tid = threadIdx.x, lane = tid & 63, w = tid >> 6;
  const int lr = lane & 15, lg = lane >> 4;
  const int rowbase = blockIdx.x * 64, cb = blockIdx.y;
  const int a = w >> 1, b = w & 1;
  vbf16x8 af[2][4];
  #pragma unroll
  for (int ar = 0; ar < 2; ++ar) {
    const u16* rp = xbf + (size_t)(rowbase + (a * 2 + ar) * 16 + lr) * 128;
    #pragma unroll
    for (int ks = 0; ks < 4; ++ks) af[ar][ks] = *(const vbf16x8*)(rp + ks * 32 + lg * 8);
  }
  vf32x4 z = {0.f, 0.f, 0.f, 0.f};
  vf32x4 acc[2][2] = {{z, z}, {z, z}};
  #pragma unroll
  for (int ks = 0; ks < 4; ++ks) {
    vbf16x8 bf[2];
    #pragma unroll
    for (int cbl = 0; cbl < 2; ++cbl) {
      int gcol = cb * 64 + (b * 2 + cbl) * 16 + lr;
      bf[cbl] = *(const vbf16x8*)(wcatT + (size_t)gcol * 128 + ks * 32 + lg * 8);
    }
    #pragma unroll
    for (int ar = 0; ar < 2; ++ar)
      #pragma unroll
      for (int cbl = 0; cbl < 2; ++cbl)
        acc[ar][cbl] = MFMA16(af[ar][ks], bf[cbl], acc[ar][cbl]);
  }
  #pragma unroll
  for (int ar = 0; ar < 2; ++ar)
    #pragma unroll
    for (int cbl = 0; cbl < 2; ++cbl) {
      int gcol = cb * 64 + (b * 2 + cbl) * 16 + lr;
      #pragma unroll
      for (int r = 0; r < 4; ++r) {
        int grow = rowbase + (a * 2 + ar) * 16 + lg * 4 + r;
        float vv = acc[ar][cbl][r];
        if (gcol < 128)      U[(size_t)grow * 128 + gcol] = vv;
        else if (gcol < 256) T[(size_t)grow * 128 + (gcol - 128)] = vv;
        else                 V[(size_t)grow * 128 + (gcol - 256)] = vv;
      }
    }
}

// ---------------- fused: softmax, G = sum_e s_e*relu(T_i+U_j+b1), h_agg, update MLP ----------------
__global__ __launch_bounds__(256) void k_msg_upd(
    const float* __restrict__ x,
    const float* __restrict__ Uarr, const float* __restrict__ Tarr, const float* __restrict__ Varr,
    const float* __restrict__ topV, const int* __restrict__ topI,
    const float* __restrict__ b1, const float* __restrict__ b2,
    const float* __restrict__ ub1, const float* __restrict__ ub2,
    const u16* __restrict__ w2T, const u16* __restrict__ u1bT, const u16* __restrict__ u2T,
    float* __restrict__ out) {
  __shared__ float wsm[32 * 20];
  __shared__ int   ism[32 * 20];
  __shared__ u16   Gbf[32 * 136];
  __shared__ u16   Hbf[32 * 136];
  const int tid = threadIdx.x, lane = tid & 63, w = tid >> 6;
  const int lr = lane & 15, lg = lane >> 4;
  const int base = blockIdx.x * 32;

  if (tid < 32) { // softmax over top-20 sims (order-independent)
    int i = base + tid;
    float vv[20]; float mx = -1e30f;
    #pragma unroll
    for (int e = 0; e < 20; ++e) { vv[e] = topV[(size_t)i * 20 + e]; mx = fmaxf(mx, vv[e]); }
    float s = 0.f;
    #pragma unroll
    for (int e = 0; e < 20; ++e) { vv[e] = __expf(vv[e] - mx); s += vv[e]; }
    float inv = 1.f / s;
    #pragma unroll
    for (int e = 0; e < 20; ++e) {
      wsm[tid * 20 + e] = vv[e] * inv;
      ism[tid * 20 + e] = topI[(size_t)i * 20 + e];
    }
  }
  __syncthreads();

  { // G step: 8 threads per row, 16 channels each
    int r = tid >> 3, q = tid & 7, ch0 = q * 16;
    int i = base + r;
    vf32x4 z = {0.f, 0.f, 0.f, 0.f};
    vf32x4 tr[4], br[4], acc[4];
    #pragma unroll
    for (int c = 0; c < 4; ++c) {
      tr[c] = *(const vf32x4*)&Tarr[(size_t)i * 128 + ch0 + c * 4];
      br[c] = *(const vf32x4*)&b1[ch0 + c * 4];
      acc[c] = z;
    }
    #pragma unroll 1
    for (int e = 0; e < 20; ++e) {
      int j = ism[r * 20 + e]; float s = wsm[r * 20 + e];
      const vf32x4* up = (const vf32x4*)&Uarr[(size_t)j * 128 + ch0];
      #pragma unroll
      for (int c = 0; c < 4; ++c) {
        vf32x4 u = up[c];
        #pragma unroll
        for (int zz = 0; zz < 4; ++zz) {
          float p = tr[c][zz] + u[zz] + br[c][zz];
          acc[c][zz] += s * fmaxf(p, 0.f);
        }
      }
    }
    #pragma unroll
    for (int c = 0; c < 4; ++c)
      #pragma unroll
      for (int zz = 0; zz < 4; ++zz)
        Gbf[r * 136 + ch0 + c * 4 + zz] = f2bf(acc[c][zz]);
  }
  __syncthreads();

  const int rt = w >> 1, cg = w & 1;
  vf32x4 z4 = {0.f, 0.f, 0.f, 0.f};
  { // GEMM1: h_agg = G @ w2 + b2 -> Hbf
    vf32x4 acc[4] = {z4, z4, z4, z4};
    #pragma unroll
    for (int ks = 0; ks < 4; ++ks) {
      vbf16x8 a = *(const vbf16x8*)&Gbf[(rt * 16 + lr) * 136 + ks * 32 + lg * 8];
      #pragma unroll
      for (int c = 0; c < 4; ++c) {
        int col = (cg * 4 + c) * 16 + lr;
        vbf16x8 bb = *(const vbf16x8*)(w2T + (size_t)col * 128 + ks * 32 + lg * 8);
        acc[c] = MFMA16(a, bb, acc[c]);
      }
    }
    #pragma unroll
    for (int c = 0; c < 4; ++c) {
      int col = (cg * 4 + c) * 16 + lr;
      float bias = b2[col];
      #pragma unroll
      for (int r = 0; r < 4; ++r) {
        int row = rt * 16 + lg * 4 + r;
        Hbf[row * 136 + col] = f2bf(acc[c][r] + bias);
      }
    }
  }
  __syncthreads();
  { // GEMM2: pre = h_agg @ uw1[128:] + V_i + ub1, relu -> Gbf (reused as P)
    vf32x4 acc[4] = {z4, z4, z4, z4};
    #pragma unroll
    for (int ks = 0; ks < 4; ++ks) {
      vbf16x8 a = *(const vbf16x8*)&Hbf[(rt * 16 + lr) * 136 + ks * 32 + lg * 8];
      #pragma unroll
      for (int c = 0; c < 4; ++c) {
        int col = (cg * 4 + c) * 16 + lr;
        vbf16x8 bb = *(const vbf16x8*)(u1bT + (size_t)col * 128 + ks * 32 + lg * 8);
        acc[c] = MFMA16(a, bb, acc[c]);
      }
    }
    #pragma unroll
    for (int c = 0; c < 4; ++c) {
      int col = (cg * 4 + c) * 16 + lr;
      float bias = ub1[col];
      #pragma unroll
      for (int r = 0; r < 4; ++r) {
        int row = rt * 16 + lg * 4 + r;
        float vv = acc[c][r] + Varr[(size_t)(base + row) * 128 + col] + bias;
        Gbf[row * 136 + col] = f2bf(fmaxf(vv, 0.f));
      }
    }
  }
  __syncthreads();
  { // GEMM3: out = x + P @ uw2 + ub2
    vf32x4 acc[4] = {z4, z4, z4, z4};
    #pragma unroll
    for (int ks = 0; ks < 4; ++ks) {
      vbf16x8 a = *(const vbf16x8*)&Gbf[(rt * 16 + lr) * 136 + ks * 32 + lg * 8];
      #pragma unroll
      for (int c = 0; c < 4; ++c) {
        int col = (cg * 4 + c) * 16 + lr;
        vbf16x8 bb = *(const vbf16x8*)(u2T + (size_t)col * 128 + ks * 32 + lg * 8);
        acc[c] = MFMA16(a, bb, acc[c]);
      }
    }
    #pragma unroll
    for (int c = 0; c < 4; ++c) {
      int col = (cg * 4 + c) * 16 + lr;
      float bias = ub2[col];
      #pragma unroll
      for (int r = 0; r < 4; ++r) {
        int row = rt * 16 + lg * 4 + r;
        size_t o = (size_t)(base + row) * 128 + col;
        out[o] = x[o] + acc[c][r] + bias;
      }
    }
  }
}

extern "C" void kernel_launch(void* const* d_in, const int* in_sizes, int n_in,
                              void* d_out, int out_size, void* d_ws, size_t ws_size,
                              hipStream_t stream) {
  (void)in_sizes; (void)n_in; (void)out_size; (void)ws_size;
  const float* x   = (const float*)d_in[0];
  const float* w1  = (const float*)d_in[1];
  const float* b1  = (const float*)d_in[2];
  const float* w2  = (const float*)d_in[3];
  const float* b2  = (const float*)d_in[4];
  const float* uw1 = (const float*)d_in[5];
  const float* ub1 = (const float*)d_in[6];
  const float* uw2 = (const float*)d_in[7];
  const float* ub2 = (const float*)d_in[8];
  float* out = (float*)d_out;
  char* ws = (char*)d_ws;

  // Live ranges: sampK [17M,65M) written by k_sim1, read by k_candsel.
  // U/T/V @ [17M,41M) written by k_pre AFTER k_candsel -> overlay OK. High-water ~67.6 MB.
  u16*   xnt   = (u16*)(ws + 0);                         // 4 MB (granule-tiled xn)
  u16*   xbf   = (u16*)(ws + (4u << 20));                // 4 MB
  float* xnf   = (float*)(ws + (8u << 20));              // 8 MB
  u16*   wcatT = (u16*)(ws + (16u << 20));               // 96 KB
  u16*   w2T   = (u16*)(ws + (16u << 20) + 131072);      // 32 KB
  u16*   u1bT  = (u16*)(ws + (16u << 20) + 163840);      // 32 KB
  u16*   u2T   = (u16*)(ws + (16u << 20) + 196608);      // 32 KB
  u32*   sampK = (u32*)(ws + (17u << 20));               // 48 MB (transient)
  float* Uarr  = (float*)(ws + (17u << 20));             // 8 MB (after sampK dead)
  float* Tarr  = (float*)(ws + (25u << 20));             // 8 MB
  float* Varr  = (float*)(ws + (33u << 20));             // 8 MB
  float* topV  = (float*)(ws + (65u << 20));             // 1.31 MB
  int*   topI  = (int*)(ws + (67u << 20));               // 1.31 MB

  hipLaunchKernelGGL(k_prep_w, dim3(384), dim3(256), 0, stream,
                     w1, w2, uw1, uw2, wcatT, w2T, u1bT, u2T);
  hipLaunchKernelGGL(k_norm, dim3(4096), dim3(256), 0, stream, x, xnf, xnt, xbf);
  hipLaunchKernelGGL(k_sim1, dim3(1024), dim3(256), 0, stream, xnt, sampK);
  hipLaunchKernelGGL(k_candsel, dim3(4096), dim3(256), 0, stream, sampK, xnf, topV, topI);
  hipLaunchKernelGGL(k_pre, dim3(256, 6), dim3(256), 0, stream, xbf, wcatT, Uarr, Tarr, Varr);
  hipLaunchKernelGGL(k_msg_upd, dim3(512), dim3(256), 0, stream,
                     x, Uarr, Tarr, Varr, topV, topI, b1, b2, ub1, ub2, w2T, u1bT, u2T, out);
}

// Round 21
// 192.044 us; speedup vs baseline: 1.0622x; 1.0028x over previous
//
#include <hip/hip_runtime.h>

typedef unsigned short u16;
typedef unsigned int u32;
typedef short vbf16x8 __attribute__((ext_vector_type(8)));   // 8 bf16 as shorts (4 VGPR)
typedef float vf32x4 __attribute__((ext_vector_type(4)));
typedef int vi32x4 __attribute__((ext_vector_type(4)));

#define MFMA16(a,b,c) __builtin_amdgcn_mfma_f32_16x16x32_bf16((a),(b),(c),0,0,0)

__device__ __forceinline__ u16 f2bf(float f) {
  union { float f; unsigned u; } c; c.f = f;
  unsigned r = c.u + 0x7fffu + ((c.u >> 16) & 1u);
  return (u16)(r >> 16);
}

// ---------------- prep: weight transposes (bf16) ----------------
__global__ __launch_bounds__(256) void k_prep_w(
    const float* __restrict__ w1, const float* __restrict__ w2,
    const float* __restrict__ u1, const float* __restrict__ u2,
    u16* __restrict__ wcatT, u16* __restrict__ w2T,
    u16* __restrict__ u1bT, u16* __restrict__ u2T) {
  int id = blockIdx.x * 256 + threadIdx.x;
  if (id < 49152) {
    int n = id >> 7, k = id & 127;
    float v;
    if (n < 128) v = w1[(128 + k) * 128 + n];
    else if (n < 256) v = w1[k * 128 + (n - 128)];
    else v = u1[k * 128 + (n - 256)];
    wcatT[id] = f2bf(v);
  } else {
    int id2 = id - 49152;
    int m = id2 >> 14, r = id2 & 16383;
    int n = r >> 7, k = r & 127;
    if (m == 0) w2T[r] = f2bf(w2[k * 128 + n]);
    else if (m == 1) u1bT[r] = f2bf(u1[(128 + k) * 128 + n]);
    else u2T[r] = f2bf(u2[k * 128 + n]);
  }
}

// ---------------- norms: xnf (f32), xbf (raw bf16), xnt (normalized bf16, MFMA-granule-tiled) ------
// xnt: granule (row j, ks, lg) at u16 offset (j>>4)*2048 + ks*512 + lg*128 + (j&15)*8.
__global__ __launch_bounds__(256) void k_norm(
    const float* __restrict__ x, float* __restrict__ xnf,
    u16* __restrict__ xnt, u16* __restrict__ xbf) {
  __shared__ u16 buf[4][128];
  int tid = threadIdx.x;
  int lane = tid & 63, w = tid >> 6;
  int row = blockIdx.x * 4 + w;
  size_t b = (size_t)row * 128;
  float v0 = x[b + lane], v1 = x[b + 64 + lane];
  float ss = v0 * v0 + v1 * v1;
  #pragma unroll
  for (int m = 32; m > 0; m >>= 1) ss += __shfl_xor(ss, m);
  float d = fmaxf(sqrtf(ss), 1e-8f);
  float n0 = v0 / d, n1 = v1 / d;
  xnf[b + lane] = n0; xnf[b + 64 + lane] = n1;
  xbf[b + lane] = f2bf(v0); xbf[b + 64 + lane] = f2bf(v1);
  buf[w][lane] = f2bf(n0); buf[w][64 + lane] = f2bf(n1);
  __syncthreads();
  if (tid < 64) {
    int r = tid >> 4, g = tid & 15;
    int grow = blockIdx.x * 4 + r;
    vi32x4 d4 = *(const vi32x4*)&buf[r][g * 8];
    *(vi32x4*)&xnt[(size_t)(grow >> 4) * 2048 + (g >> 2) * 512 + (g & 3) * 128 + (grow & 15) * 8] = d4;
  }
}

// ---------------- single sim pass: per-(row,seg-stream) top-3 FLOAT KEYS ---------------------------
// two4 = {2,2,2,2} persistent register fed as C of the FIRST MFMA (D gets fresh regs -> no acc-init
// movs). acc[r] = sim+2 in (1,3].
// key = float_bits(acc) & ~0x3F | t; per-value cost: and_or + max + 2x med3 = 4 VALU.
// Block: 256 rows (4 waves x 64 rows) x one 1024-col segment. Grid 1024.
__global__ __launch_bounds__(256, 2) void k_sim1(
    const u16* __restrict__ xnt, u32* __restrict__ sampK) {
  const int tid = threadIdx.x, lane = tid & 63, w = tid >> 6;
  const int lr = lane & 15, lg = lane >> 4;
  const int seg = blockIdx.x & 15, rbk = blockIdx.x >> 4;
  const int rowbase = rbk * 256 + w * 64;

  vbf16x8 af[4][4];
  #pragma unroll
  for (int a = 0; a < 4; ++a) {
    const u16* tp = xnt + (size_t)((rowbase >> 4) + a) * 2048;
    #pragma unroll
    for (int ks = 0; ks < 4; ++ks)
      af[a][ks] = *(const vbf16x8*)(tp + ks * 512 + lg * 128 + lr * 8);
  }

  float k1[4][4], k2[4][4], k3[4][4];
  #pragma unroll
  for (int a = 0; a < 4; ++a)
    #pragma unroll
    for (int r = 0; r < 4; ++r) { k1[a][r] = 0.f; k2[a][r] = 0.f; k3[a][r] = 0.f; }

  const vf32x4 two4 = {2.0f, 2.0f, 2.0f, 2.0f};

  const u16* segp = xnt + (size_t)(seg * 64) * 2048;
  vbf16x8 bc[4], bn[4];
  #pragma unroll
  for (int ks = 0; ks < 4; ++ks) bc[ks] = *(const vbf16x8*)(segp + ks * 512 + lane * 8);

#define S1STEP(B, TKEY) { \
  _Pragma("unroll") \
  for (int a = 0; a < 4; ++a) { \
    vf32x4 acc = MFMA16(af[a][0], (B)[0], two4); \
    _Pragma("unroll") \
    for (int ks = 1; ks < 4; ++ks) acc = MFMA16(af[a][ks], (B)[ks], acc); \
    _Pragma("unroll") \
    for (int r = 0; r < 4; ++r) { \
      union { u32 u; float f; } kc; \
      kc.u = (__float_as_uint(acc[r]) & 0xFFFFFFC0u) | (TKEY); \
      float kv = kc.f; \
      float nk1 = fmaxf(k1[a][r], kv); \
      float nk2 = __builtin_amdgcn_fmed3f(k1[a][r], k2[a][r], kv); \
      float nk3 = __builtin_amdgcn_fmed3f(k2[a][r], k3[a][r], kv); \
      k1[a][r] = nk1; k2[a][r] = nk2; k3[a][r] = nk3; \
    } } }

  #pragma unroll 1
  for (int ti = 0; ti < 32; ++ti) {
    { const u16* tp1 = segp + (size_t)(2 * ti + 1) * 2048;
      #pragma unroll
      for (int ks = 0; ks < 4; ++ks) bn[ks] = *(const vbf16x8*)(tp1 + ks * 512 + lane * 8); }
    S1STEP(bc, (u32)(2 * ti));
    { int nt = (ti < 31) ? (2 * ti + 2) : 63;
      const u16* tp2 = segp + (size_t)nt * 2048;
      #pragma unroll
      for (int ks = 0; ks < 4; ++ks) bc[ks] = *(const vbf16x8*)(tp2 + ks * 512 + lane * 8); }
    S1STEP(bn, (u32)(2 * ti + 1));
  }

  // dump 48 keys per (row, seg): sampK[row*768 + seg*48 + slot*16 + lr]
  #pragma unroll
  for (int a = 0; a < 4; ++a)
    #pragma unroll
    for (int r = 0; r < 4; ++r) {
      int row = rowbase + a * 16 + lg * 4 + r;
      u32* dp = sampK + (size_t)row * 768 + seg * 48;
      dp[lr] = __float_as_uint(k1[a][r]);
      dp[16 + lr] = __float_as_uint(k2[a][r]);
      dp[32 + lr] = __float_as_uint(k3[a][r]);
    }
}

// ---------------- merged cand+select: wave per row, ballot-bisection order statistics --------------
// theta: 14-iter u32 bisection; invariant lo <= true-28th at EVERY iteration, so shortening only
// widens capture by <= 3.4e-4 (safe direction). mn: 16-iter float bisection, slack 4.6e-5
// absorbed by the +6e-5 A-guard. Margin chain: capture >= 28th-6e-3 covers window wLo = flo-5e-3
// since 28th <= 20th <= flo+4.6e-5 (1e-3 headroom).
__global__ __launch_bounds__(256) void k_candsel(
    const u32* __restrict__ sampK, const float* __restrict__ xnf,
    float* __restrict__ topV, int* __restrict__ topI) {
  __shared__ u32   keys3[4][256];    // only slot-2 (3rd-best) keys are ever read cross-lane
  __shared__ float svals[4][384];
  __shared__ int   sidx[4][384];
  __shared__ int   wlist[4][48];
  __shared__ float wex[4][48];
  const int tid = threadIdx.x, lane = tid & 63, w = tid >> 6;
  const int i = blockIdx.x * 4 + w;
  const u32* sp = sampK + (size_t)i * 768;
  u32 kq[12];
  #pragma unroll
  for (int q = 0; q < 12; ++q) {
    kq[q] = sp[q * 64 + lane];
    int f = q * 64 + lane;
    int i16 = f >> 4;
    int sg = (i16 * 171) >> 9;          // i16 / 3 (exact for 0..47)
    int slot = i16 - sg * 3;
    if (slot == 2) keys3[w][sg * 16 + (f & 15)] = kq[q];
  }

  // theta: 14-iter u32 bisection for 28th-largest key; lo <= true28 invariant
  u32 lo = 0x3F000000u, hi = 0x40600000u;   // keys = bits(sim+2) in (0.5, 3.5) always
  #pragma unroll 1
  for (int it = 0; it < 14; ++it) {
    u32 mid = lo + ((hi - lo) >> 1);
    int cl = 0;
    #pragma unroll
    for (int q = 0; q < 12; ++q) cl += (kq[q] >= mid) ? 1 : 0;
    int tot = __popcll(__ballot((cl & 1) != 0))
            + 2 * __popcll(__ballot((cl & 2) != 0))
            + 4 * __popcll(__ballot((cl & 4) != 0))
            + 8 * __popcll(__ballot((cl & 8) != 0));
    if (tot >= 28) lo = mid; else hi = mid;
  }
  // widen by 6e-3 in value space (> select window 5e-3 + bisection/quant slop)
  float dec = __uint_as_float(lo & 0xFFFFFFC0u);
  const u32 th = __float_as_uint(dec - 6e-3f) & 0xFFFFFFC0u;

  int cbase = 0;
  // keyed emission from UNFLAGGED streams -> LDS
  #pragma unroll
  for (int q = 0; q < 12; ++q) {
    int f = q * 64 + lane;
    int i16 = f >> 4;
    int sg = (i16 * 171) >> 9;
    int lrr = f & 15;
    u32 key3 = keys3[w][sg * 16 + lrr];
    bool e = (kq[q] >= th) && (key3 < th);
    unsigned long long ball = __ballot(e);
    if (e) {
      int pos = cbase + __popcll(ball & ((1ull << lane) - 1ull));
      if (pos < 384) {
        svals[w][pos] = __uint_as_float(kq[q] & 0xFFFFFFC0u) - 2.0f;
        sidx[w][pos] = sg * 1024 + (int)(kq[q] & 63u) * 16 + lrr;
      }
    }
    cbase += __popcll(ball);
  }
  if (cbase > 384) cbase = 384;
  // expansion: flagged streams -> all 64 member cols, sentinel value
  #pragma unroll 1
  for (int t = 0; t < 4; ++t) {
    int strm = t * 64 + lane;
    int sg = strm >> 4, lrr = strm & 15;
    bool fl = keys3[w][sg * 16 + lrr] >= th;
    unsigned long long mask = __ballot(fl);
    while (mask != 0ull && cbase + 64 <= 384) {
      int b = __ffsll((long long)mask) - 1;
      mask &= mask - 1ull;
      int strmb = t * 64 + b;
      int sgb = strmb >> 4, lrb = strmb & 15;
      svals[w][cbase + lane] = -1e30f;
      sidx[w][cbase + lane] = sgb * 1024 + lane * 16 + lrb;
      cbase += 64;
    }
  }
  const int c = cbase;

  const int g = lane >> 3, sl = lane & 7;
  const float* xip = &xnf[(size_t)i * 128 + sl * 16];
  vf32x4 xi0 = *(const vf32x4*)&xip[0];
  vf32x4 xi1 = *(const vf32x4*)&xip[4];
  vf32x4 xi2 = *(const vf32x4*)&xip[8];
  vf32x4 xi3 = *(const vf32x4*)&xip[12];

  // phase 0: exact rescore of sentinel (expansion) items
  #pragma unroll 1
  for (int s = g; s < c; s += 8) {
    if (svals[w][s] == -1e30f) {
      int j = sidx[w][s];
      const float* xjp = &xnf[(size_t)j * 128 + sl * 16];
      vf32x4 a0 = *(const vf32x4*)&xjp[0];
      vf32x4 a1 = *(const vf32x4*)&xjp[4];
      vf32x4 a2 = *(const vf32x4*)&xjp[8];
      vf32x4 a3 = *(const vf32x4*)&xjp[12];
      float p = xi0[0]*a0[0] + xi0[1]*a0[1] + xi0[2]*a0[2] + xi0[3]*a0[3]
              + xi1[0]*a1[0] + xi1[1]*a1[1] + xi1[2]*a1[2] + xi1[3]*a1[3]
              + xi2[0]*a2[0] + xi2[1]*a2[1] + xi2[2]*a2[2] + xi2[3]*a2[3]
              + xi3[0]*a3[0] + xi3[1]*a3[1] + xi3[2]*a3[2] + xi3[3]*a3[3];
      p += __shfl_xor(p, 1); p += __shfl_xor(p, 2); p += __shfl_xor(p, 4);
      if (sl == 0) svals[w][s] = p;
    }
  }

  // load per-lane candidate slices
  float v[6]; int ix[6]; bool ok[6];
  #pragma unroll
  for (int h = 0; h < 6; ++h) {
    int s = h * 64 + lane;
    ok[h] = s < c;
    v[h] = ok[h] ? svals[w][s] : -1e30f;
    ix[h] = ok[h] ? sidx[w][s] : 0x7fffffff;
  }

  // mn: bisect float space for the 20th-largest captured v; flo <= mn_true < flo + 4.6e-5
  float flo = -1.5f, fhi = 1.5f;
  #pragma unroll 1
  for (int it = 0; it < 16; ++it) {
    float mid = 0.5f * (flo + fhi);
    int cl = 0;
    #pragma unroll
    for (int h = 0; h < 6; ++h) cl += (ok[h] && v[h] >= mid) ? 1 : 0;
    int tot = __popcll(__ballot((cl & 1) != 0))
            + 2 * __popcll(__ballot((cl & 2) != 0))
            + 4 * __popcll(__ballot((cl & 4) != 0));
    if (tot >= 20) flo = mid; else fhi = mid;
  }

  // A / W classification (bisection slack 4.6e-5 absorbed by +6e-5 guard)
  const float M2 = 5e-3f;
  const float aThr = flo + M2 + 6e-5f;
  const float wLo  = flo - M2;
  bool isA[6], isW[6]; int wp[6];
  int nA = 0, wbase = 0;
  #pragma unroll
  for (int h = 0; h < 6; ++h) {
    isA[h] = ok[h] && v[h] > aThr;
    isW[h] = ok[h] && (v[h] >= wLo) && (v[h] <= aThr);
    unsigned long long ba = __ballot(isA[h]);
    nA += __popcll(ba);
    unsigned long long bw = __ballot(isW[h]);
    wp[h] = wbase + __popcll(bw & ((1ull << lane) - 1ull));
    if (isW[h] && wp[h] < 48) wlist[w][wp[h]] = ix[h];
    wbase += __popcll(bw);
  }
  int nW = (wbase > 48) ? 48 : wbase;

  // exact rescore of W (8 groups x 8 lanes)
  #pragma unroll 1
  for (int t = g; t < nW; t += 8) {
    int j = wlist[w][t];
    const float* xjp = &xnf[(size_t)j * 128 + sl * 16];
    vf32x4 a0 = *(const vf32x4*)&xjp[0];
    vf32x4 a1 = *(const vf32x4*)&xjp[4];
    vf32x4 a2 = *(const vf32x4*)&xjp[8];
    vf32x4 a3 = *(const vf32x4*)&xjp[12];
    float p = xi0[0]*a0[0] + xi0[1]*a0[1] + xi0[2]*a0[2] + xi0[3]*a0[3]
            + xi1[0]*a1[0] + xi1[1]*a1[1] + xi1[2]*a1[2] + xi1[3]*a1[3]
            + xi2[0]*a2[0] + xi2[1]*a2[1] + xi2[2]*a2[2] + xi2[3]*a2[3]
            + xi3[0]*a3[0] + xi3[1]*a3[1] + xi3[2]*a3[2] + xi3[3]*a3[3];
    p += __shfl_xor(p, 1); p += __shfl_xor(p, 2); p += __shfl_xor(p, 4);
    if (sl == 0) wex[w][t] = p;
  }

  float e[6]; int rw[6];
  #pragma unroll
  for (int h = 0; h < 6; ++h) { e[h] = -1e30f; rw[h] = 0; }
  #pragma unroll
  for (int h = 0; h < 6; ++h)
    if (isW[h] && wp[h] < 48) e[h] = wex[w][wp[h]];
  #pragma unroll 1
  for (int t = 0; t < nW; ++t) {
    float et = wex[w][t]; int jt = wlist[w][t];
    #pragma unroll
    for (int h = 0; h < 6; ++h)
      rw[h] += (et > e[h] || (et == e[h] && jt < ix[h])) ? 1 : 0;
  }
  const int need = 20 - nA;
  int base = 0;
  #pragma unroll
  for (int h = 0; h < 6; ++h) {
    bool fw = isW[h] && (wp[h] < 48) && rw[h] < need;
    bool fin = isA[h] || fw;
    float o = isA[h] ? v[h] : e[h];
    unsigned long long bf = __ballot(fin);
    if (fin) {
      int pos = base + __popcll(bf & ((1ull << lane) - 1ull));
      topV[(size_t)i * 20 + pos] = o; topI[(size_t)i * 20 + pos] = ix[h];
    }
    base += __popcll(bf);
  }
}

// ---------------- precompute U = x@w1[128:], T = x@w1[:128], V = x@uw1[:128] ----------------
__global__ __launch_bounds__(256) void k_pre(
    const u16* __restrict__ xbf, const u16* __restrict__ wcatT,
    float* __restrict__ U, float* __restrict__ T, float* __restrict__ V) {
  const int tid = threadIdx.x, lane = tid & 63, w = tid >> 6;
  const int lr = lane & 15, lg = lane >> 4;
  const int rowbase = blockIdx.x * 64, cb = blockIdx.y;
  const int a = w >> 1, b = w & 1;
  vbf16x8 af[2][4];
  #pragma unroll
  for (int ar = 0; ar < 2; ++ar) {
    const u16* rp = xbf + (size_t)(rowbase + (a * 2 + ar) * 16 + lr) * 128;
    #pragma unroll
    for (int ks = 0; ks < 4; ++ks) af[ar][ks] = *(const vbf16x8*)(rp + ks * 32 + lg * 8);
  }
  vf32x4 z = {0.f, 0.f, 0.f, 0.f};
  vf32x4 acc[2][2] = {{z, z}, {z, z}};
  #pragma unroll
  for (int ks = 0; ks < 4; ++ks) {
    vbf16x8 bf[2];
    #pragma unroll
    for (int cbl = 0; cbl < 2; ++cbl) {
      int gcol = cb * 64 + (b * 2 + cbl) * 16 + lr;
      bf[cbl] = *(const vbf16x8*)(wcatT + (size_t)gcol * 128 + ks * 32 + lg * 8);
    }
    #pragma unroll
    for (int ar = 0; ar < 2; ++ar)
      #pragma unroll
      for (int cbl = 0; cbl < 2; ++cbl)
        acc[ar][cbl] = MFMA16(af[ar][ks], bf[cbl], acc[ar][cbl]);
  }
  #pragma unroll
  for (int ar = 0; ar < 2; ++ar)
    #pragma unroll
    for (int cbl = 0; cbl < 2; ++cbl) {
      int gcol = cb * 64 + (b * 2 + cbl) * 16 + lr;
      #pragma unroll
      for (int r = 0; r < 4; ++r) {
        int grow = rowbase + (a * 2 + ar) * 16 + lg * 4 + r;
        float vv = acc[ar][cbl][r];
        if (gcol < 128)      U[(size_t)grow * 128 + gcol] = vv;
        else if (gcol < 256) T[(size_t)grow * 128 + (gcol - 128)] = vv;
        else                 V[(size_t)grow * 128 + (gcol - 256)] = vv;
      }
    }
}

// ---------------- fused: softmax, G = sum_e s_e*relu(T_i+U_j+b1), h_agg, update MLP ----------------
__global__ __launch_bounds__(256) void k_msg_upd(
    const float* __restrict__ x,
    const float* __restrict__ Uarr, const float* __restrict__ Tarr, const float* __restrict__ Varr,
    const float* __restrict__ topV, const int* __restrict__ topI,
    const float* __restrict__ b1, const float* __restrict__ b2,
    const float* __restrict__ ub1, const float* __restrict__ ub2,
    const u16* __restrict__ w2T, const u16* __restrict__ u1bT, const u16* __restrict__ u2T,
    float* __restrict__ out) {
  __shared__ float wsm[32 * 20];
  __shared__ int   ism[32 * 20];
  __shared__ u16   Gbf[32 * 136];
  __shared__ u16   Hbf[32 * 136];
  const int tid = threadIdx.x, lane = tid & 63, w = tid >> 6;
  const int lr = lane & 15, lg = lane >> 4;
  const int base = blockIdx.x * 32;

  if (tid < 32) { // softmax over top-20 sims (order-independent)
    int i = base + tid;
    float vv[20]; float mx = -1e30f;
    #pragma unroll
    for (int e = 0; e < 20; ++e) { vv[e] = topV[(size_t)i * 20 + e]; mx = fmaxf(mx, vv[e]); }
    float s = 0.f;
    #pragma unroll
    for (int e = 0; e < 20; ++e) { vv[e] = __expf(vv[e] - mx); s += vv[e]; }
    float inv = 1.f / s;
    #pragma unroll
    for (int e = 0; e < 20; ++e) {
      wsm[tid * 20 + e] = vv[e] * inv;
      ism[tid * 20 + e] = topI[(size_t)i * 20 + e];
    }
  }
  __syncthreads();

  { // G step: 8 threads per row, 16 channels each
    int r = tid >> 3, q = tid & 7, ch0 = q * 16;
    int i = base + r;
    vf32x4 z = {0.f, 0.f, 0.f, 0.f};
    vf32x4 tr[4], br[4], acc[4];
    #pragma unroll
    for (int c = 0; c < 4; ++c) {
      tr[c] = *(const vf32x4*)&Tarr[(size_t)i * 128 + ch0 + c * 4];
      br[c] = *(const vf32x4*)&b1[ch0 + c * 4];
      acc[c] = z;
    }
    #pragma unroll 1
    for (int e = 0; e < 20; ++e) {
      int j = ism[r * 20 + e]; float s = wsm[r * 20 + e];
      const vf32x4* up = (const vf32x4*)&Uarr[(size_t)j * 128 + ch0];
      #pragma unroll
      for (int c = 0; c < 4; ++c) {
        vf32x4 u = up[c];
        #pragma unroll
        for (int zz = 0; zz < 4; ++zz) {
          float p = tr[c][zz] + u[zz] + br[c][zz];
          acc[c][zz] += s * fmaxf(p, 0.f);
        }
      }
    }
    #pragma unroll
    for (int c = 0; c < 4; ++c)
      #pragma unroll
      for (int zz = 0; zz < 4; ++zz)
        Gbf[r * 136 + ch0 + c * 4 + zz] = f2bf(acc[c][zz]);
  }
  __syncthreads();

  const int rt = w >> 1, cg = w & 1;
  vf32x4 z4 = {0.f, 0.f, 0.f, 0.f};
  { // GEMM1: h_agg = G @ w2 + b2 -> Hbf
    vf32x4 acc[4] = {z4, z4, z4, z4};
    #pragma unroll
    for (int ks = 0; ks < 4; ++ks) {
      vbf16x8 a = *(const vbf16x8*)&Gbf[(rt * 16 + lr) * 136 + ks * 32 + lg * 8];
      #pragma unroll
      for (int c = 0; c < 4; ++c) {
        int col = (cg * 4 + c) * 16 + lr;
        vbf16x8 bb = *(const vbf16x8*)(w2T + (size_t)col * 128 + ks * 32 + lg * 8);
        acc[c] = MFMA16(a, bb, acc[c]);
      }
    }
    #pragma unroll
    for (int c = 0; c < 4; ++c) {
      int col = (cg * 4 + c) * 16 + lr;
      float bias = b2[col];
      #pragma unroll
      for (int r = 0; r < 4; ++r) {
        int row = rt * 16 + lg * 4 + r;
        Hbf[row * 136 + col] = f2bf(acc[c][r] + bias);
      }
    }
  }
  __syncthreads();
  { // GEMM2: pre = h_agg @ uw1[128:] + V_i + ub1, relu -> Gbf (reused as P)
    vf32x4 acc[4] = {z4, z4, z4, z4};
    #pragma unroll
    for (int ks = 0; ks < 4; ++ks) {
      vbf16x8 a = *(const vbf16x8*)&Hbf[(rt * 16 + lr) * 136 + ks * 32 + lg * 8];
      #pragma unroll
      for (int c = 0; c < 4; ++c) {
        int col = (cg * 4 + c) * 16 + lr;
        vbf16x8 bb = *(const vbf16x8*)(u1bT + (size_t)col * 128 + ks * 32 + lg * 8);
        acc[c] = MFMA16(a, bb, acc[c]);
      }
    }
    #pragma unroll
    for (int c = 0; c < 4; ++c) {
      int col = (cg * 4 + c) * 16 + lr;
      float bias = ub1[col];
      #pragma unroll
      for (int r = 0; r < 4; ++r) {
        int row = rt * 16 + lg * 4 + r;
        float vv = acc[c][r] + Varr[(size_t)(base + row) * 128 + col] + bias;
        Gbf[row * 136 + col] = f2bf(fmaxf(vv, 0.f));
      }
    }
  }
  __syncthreads();
  { // GEMM3: out = x + P @ uw2 + ub2
    vf32x4 acc[4] = {z4, z4, z4, z4};
    #pragma unroll
    for (int ks = 0; ks < 4; ++ks) {
      vbf16x8 a = *(const vbf16x8*)&Gbf[(rt * 16 + lr) * 136 + ks * 32 + lg * 8];
      #pragma unroll
      for (int c = 0; c < 4; ++c) {
        int col = (cg * 4 + c) * 16 + lr;
        vbf16x8 bb = *(const vbf16x8*)(u2T + (size_t)col * 128 + ks * 32 + lg * 8);
        acc[c] = MFMA16(a, bb, acc[c]);
      }
    }
    #pragma unroll
    for (int c = 0; c < 4; ++c) {
      int col = (cg * 4 + c) * 16 + lr;
      float bias = ub2[col];
      #pragma unroll
      for (int r = 0; r < 4; ++r) {
        int row = rt * 16 + lg * 4 + r;
        size_t o = (size_t)(base + row) * 128 + col;
        out[o] = x[o] + acc[c][r] + bias;
      }
    }
  }
}

extern "C" void kernel_launch(void* const* d_in, const int* in_sizes, int n_in,
                              void* d_out, int out_size, void* d_ws, size_t ws_size,
                              hipStream_t stream) {
  (void)in_sizes; (void)n_in; (void)out_size; (void)ws_size;
  const float* x   = (const float*)d_in[0];
  const float* w1  = (const float*)d_in[1];
  const float* b1  = (const float*)d_in[2];
  const float* w2  = (const float*)d_in[3];
  const float* b2  = (const float*)d_in[4];
  const float* uw1 = (const float*)d_in[5];
  const float* ub1 = (const float*)d_in[6];
  const float* uw2 = (const float*)d_in[7];
  const float* ub2 = (const float*)d_in[8];
  float* out = (float*)d_out;
  char* ws = (char*)d_ws;

  // Live ranges: sampK [17M,65M) written by k_sim1, read by k_candsel.
  // U/T/V @ [17M,41M) written by k_pre AFTER k_candsel -> overlay OK. High-water ~67.6 MB.
  u16*   xnt   = (u16*)(ws + 0);                         // 4 MB (granule-tiled xn)
  u16*   xbf   = (u16*)(ws + (4u << 20));                // 4 MB
  float* xnf   = (float*)(ws + (8u << 20));              // 8 MB
  u16*   wcatT = (u16*)(ws + (16u << 20));               // 96 KB
  u16*   w2T   = (u16*)(ws + (16u << 20) + 131072);      // 32 KB
  u16*   u1bT  = (u16*)(ws + (16u << 20) + 163840);      // 32 KB
  u16*   u2T   = (u16*)(ws + (16u << 20) + 196608);      // 32 KB
  u32*   sampK = (u32*)(ws + (17u << 20));               // 48 MB (transient)
  float* Uarr  = (float*)(ws + (17u << 20));             // 8 MB (after sampK dead)
  float* Tarr  = (float*)(ws + (25u << 20));             // 8 MB
  float* Varr  = (float*)(ws + (33u << 20));             // 8 MB
  float* topV  = (float*)(ws + (65u << 20));             // 1.31 MB
  int*   topI  = (int*)(ws + (67u << 20));               // 1.31 MB

  hipLaunchKernelGGL(k_prep_w, dim3(384), dim3(256), 0, stream,
                     w1, w2, uw1, uw2, wcatT, w2T, u1bT, u2T);
  hipLaunchKernelGGL(k_norm, dim3(4096), dim3(256), 0, stream, x, xnf, xnt, xbf);
  hipLaunchKernelGGL(k_sim1, dim3(1024), dim3(256), 0, stream, xnt, sampK);
  hipLaunchKernelGGL(k_candsel, dim3(4096), dim3(256), 0, stream, sampK, xnf, topV, topI);
  hipLaunchKernelGGL(k_pre, dim3(256, 6), dim3(256), 0, stream, xbf, wcatT, Uarr, Tarr, Varr);
  hipLaunchKernelGGL(k_msg_upd, dim3(512), dim3(256), 0, stream,
                     x, Uarr, Tarr, Varr, topV, topI, b1, b2, ub1, ub2, w2T, u1bT, u2T, out);
}